// Round 4
// baseline (119.978 us; speedup 1.0000x reference)
//
#include <hip/hip_runtime.h>
#include <math.h>
#include <stdint.h>

#define SEQ 2048
#define DM  1024
#define NH  16
#define HD  64
#define TRI 3072  // 3*DM
#define NSPLIT 2  // KV-split factor

typedef _Float16 half8 __attribute__((ext_vector_type(8)));
typedef float f32x4 __attribute__((ext_vector_type(4)));

// global -> LDS direct 16B copy. LDS dest is wave-uniform base; HW adds lane*16.
#define GLOAD_LDS16(g, l)                                       \
  __builtin_amdgcn_global_load_lds(                             \
      (__attribute__((address_space(1))) void*)(g),             \
      (__attribute__((address_space(3))) void*)(l), 16, 0, 0)

// ---------------------------------------------------------------------------
// fp32 -> fp16 conversion (query/qkv_w/out_w) + RoPE cos/sin table fill.
// ---------------------------------------------------------------------------
__global__ __launch_bounds__(256)
void cvt3(const float* __restrict__ s1, const float* __restrict__ s2,
          const float* __restrict__ s3, _Float16* __restrict__ d1,
          _Float16* __restrict__ d2, _Float16* __restrict__ d3,
          float2* __restrict__ tab, int n1, int n2) {
  int b = blockIdx.x;
  if (b >= 6144) {
    int i = (b - 6144) * 256 + threadIdx.x;     // 0..65535 -> (s, d)
    int s = i >> 5, d = i & 31;
    float inv = exp2f((float)d * -0.4152410118609203f);  // theta^(-d/32)
    float ang = (float)s * inv;
    float sn, cs;
    sincosf(ang, &sn, &cs);
    tab[i] = make_float2(cs, sn);
    return;
  }
  int i = (b * 256 + threadIdx.x) * 4;
  const float* s; _Float16* d;
  if (i < n1)            { s = s1; d = d1; }
  else if (i < n1 + n2)  { s = s2; d = d2; i -= n1; }
  else                   { s = s3; d = d3; i -= n1 + n2; }
  float4 v = *(const float4*)(s + i);
  union { _Float16 h[4]; uint2 u; } pk;
  pk.h[0] = (_Float16)v.x; pk.h[1] = (_Float16)v.y;
  pk.h[2] = (_Float16)v.z; pk.h[3] = (_Float16)v.w;
  *(uint2*)(d + i) = pk.u;
}

// ---------------------------------------------------------------------------
// C[M][N] = A[M][K] (fp16) * B[N][K]^T (fp16) + bias[N], fp32 accum.
// 64x128 tile, BK=32, 4 waves, double-buffered LDS, one barrier per k-step.
// ROPE=1: fuse RoPE on q/k sections (N=3072 qkv layout) + 1/8 scale on q.
// ---------------------------------------------------------------------------
template<int ROPE, typename OutT>
__global__ __launch_bounds__(256)
void gemm_dbuf(const _Float16* __restrict__ A, const _Float16* __restrict__ B,
               const float* __restrict__ bias, const float2* __restrict__ tab,
               OutT* __restrict__ C, int M, int N, int K) {
  __shared__ _Float16 As[2][64 * 32];
  __shared__ _Float16 Bs[2][128 * 32];

  const int t = threadIdx.x, lane = t & 63, wv = t >> 6;
  const int l15 = lane & 15, l4 = lane >> 4;
  const int wr = wv >> 1, wc = wv & 1;
  const int bm = blockIdx.y * 64, bn = blockIdx.x * 128;

  auto stage = [&](int buf, int k0) {
    {
      int c = t;
      GLOAD_LDS16(A + (size_t)(bm + (c >> 2)) * K + k0 + (c & 3) * 8,
                  (char*)&As[buf][wv * 512]);
    }
    #pragma unroll
    for (int i = 0; i < 2; ++i) {
      int c = t + i * 256;
      GLOAD_LDS16(B + (size_t)(bn + (c >> 2)) * K + k0 + (c & 3) * 8,
                  (char*)&Bs[buf][(i * 256 + wv * 64) * 8]);
    }
  };

  f32x4 acc[2][4] = {};
  stage(0, 0);
  __syncthreads();

  const int nk = K / 32;
  for (int s = 0; s < nk; ++s) {
    int cur = s & 1;
    if (s + 1 < nk) stage(cur ^ 1, (s + 1) * 32);
    half8 af[2], bf[4];
    #pragma unroll
    for (int mf = 0; mf < 2; ++mf)
      af[mf] = *(const half8*)&As[cur][(wr * 32 + mf * 16 + l15) * 32 + l4 * 8];
    #pragma unroll
    for (int nf = 0; nf < 4; ++nf)
      bf[nf] = *(const half8*)&Bs[cur][(wc * 64 + nf * 16 + l15) * 32 + l4 * 8];
    __builtin_amdgcn_s_setprio(1);
    #pragma unroll
    for (int mf = 0; mf < 2; ++mf)
      #pragma unroll
      for (int nf = 0; nf < 4; ++nf)
        acc[mf][nf] = __builtin_amdgcn_mfma_f32_16x16x32_f16(
            af[mf], bf[nf], acc[mf][nf], 0, 0, 0);
    __builtin_amdgcn_s_setprio(0);
    __syncthreads();
  }

  const int sec = ROPE ? (bn >> 10) : 2;  // 0=q, 1=k, 2=v
  float bv[4];
  #pragma unroll
  for (int nf = 0; nf < 4; ++nf) bv[nf] = bias[bn + wc * 64 + nf * 16 + l15];
  #pragma unroll
  for (int mf = 0; mf < 2; ++mf)
    #pragma unroll
    for (int r = 0; r < 4; ++r) {
      int row = bm + wr * 32 + mf * 16 + l4 * 4 + r;
      float v0 = acc[mf][0][r] + bv[0];
      float v1 = acc[mf][1][r] + bv[1];
      float v2 = acc[mf][2][r] + bv[2];
      float v3 = acc[mf][3][r] + bv[3];
      if (ROPE && sec < 2) {
        float2 cs0 = tab[row * 32 + l15];
        float2 cs1 = tab[row * 32 + 16 + l15];
        float a0 = v0 * cs0.x - v2 * cs0.y;
        float a2 = v2 * cs0.x + v0 * cs0.y;
        float a1 = v1 * cs1.x - v3 * cs1.y;
        float a3 = v3 * cs1.x + v1 * cs1.y;
        if (sec == 0) { a0 *= 0.125f; a1 *= 0.125f; a2 *= 0.125f; a3 *= 0.125f; }
        v0 = a0; v1 = a1; v2 = a2; v3 = a3;
      }
      OutT* cr = C + (size_t)row * N + bn + wc * 64 + l15;
      cr[0]  = (OutT)v0; cr[16] = (OutT)v1;
      cr[32] = (OutT)v2; cr[48] = (OutT)v3;
    }
}

// ---------------------------------------------------------------------------
// MFMA flash attention with KV-split. blockIdx.z = key-chunk (1024 keys).
// Emits normalized partial O (fp16) + per-q (m, l) for the merge kernel.
// LDS = 40960 B -> 4 blocks/CU; 16 waves/CU.
// ---------------------------------------------------------------------------
__global__ __launch_bounds__(256)
void attn_f16(const _Float16* __restrict__ qkv, _Float16* __restrict__ po,
              float* __restrict__ pm, float* __restrict__ pl) {
  __shared__ _Float16 Kl[2][64 * 64];   // [k][d], 16B chunk p stored at p^(k&7)
  __shared__ _Float16 Vt[2][64 * 64];   // [d][k], 16B chunk p stored at p^(d&7)
  __shared__ _Float16 Pl[4][1024];      // per-wave P [q][k], chunk-XOR swizzled

  const int t = threadIdx.x, lane = t & 63, wv = t >> 6;
  const int l15 = lane & 15, l4 = lane >> 4;
  const int h = blockIdx.y, q0 = blockIdx.x * 64;
  const int z = blockIdx.z;
  const int kt0 = z * (SEQ / NSPLIT);

  const _Float16* Qb = qkv + h * HD;
  const _Float16* Kb = qkv + DM + h * HD;
  const _Float16* Vb = qkv + 2 * DM + h * HD;

  half8 qf[2];
  {
    const _Float16* qrow = Qb + (size_t)(q0 + wv * 16 + l15) * TRI;
    qf[0] = *(const half8*)(qrow + l4 * 8);
    qf[1] = *(const half8*)(qrow + 32 + l4 * 8);
  }

  uint4 vreg[2];

  auto issueK = [&](int buf, int kt) {
    #pragma unroll
    for (int i = 0; i < 2; ++i) {
      int c = t + i * 256, r = c >> 3, p = c & 7;
      GLOAD_LDS16(Kb + (size_t)(kt + r) * TRI + ((p ^ (r & 7)) * 8),
                  (char*)&Kl[buf][(i * 256 + wv * 64) * 8]);
    }
  };
  auto issueV = [&](int kt) {
    #pragma unroll
    for (int i = 0; i < 2; ++i)
      vreg[i] = *(const uint4*)(Vb + (size_t)(kt + lane) * TRI + (wv + i * 4) * 8);
  };
  auto writeV = [&](int buf) {
    const int m = lane & 3, k0 = lane & 60;
    #pragma unroll
    for (int i = 0; i < 2; ++i) {
      uint32_t u0 = vreg[i].x, u1 = vreg[i].y, u2 = vreg[i].z, u3 = vreg[i].w;
      uint32_t s0 = __shfl_xor(u1, 1), s1 = __shfl_xor(u0, 1);
      uint32_t s2 = __shfl_xor(u3, 1), s3 = __shfl_xor(u2, 1);
      bool b0 = (m & 1);
      uint32_t a0 = b0 ? s0 : u0, a1 = b0 ? u1 : s1;
      uint32_t a2 = b0 ? s2 : u2, a3 = b0 ? u3 : s3;
      uint32_t r0 = __shfl_xor(a2, 2), r1 = __shfl_xor(a3, 2);
      uint32_t r2 = __shfl_xor(a0, 2), r3 = __shfl_xor(a1, 2);
      bool b1 = (m & 2);
      uint32_t w0 = b1 ? r0 : a0, w1 = b1 ? r1 : a1;
      uint32_t w2 = b1 ? a2 : r2, w3 = b1 ? a3 : r3;
      int d0 = (wv + i * 4) * 8 + 2 * m;
      uint32_t lo01 = (w0 & 0xffffu) | (w1 << 16);
      uint32_t lo23 = (w2 & 0xffffu) | (w3 << 16);
      uint32_t hi01 = (w0 >> 16) | (w1 & 0xffff0000u);
      uint32_t hi23 = (w2 >> 16) | (w3 & 0xffff0000u);
      char* base = (char*)Vt[buf];
      int hb = ((k0 >> 2) & 1) * 8;
      *(uint2*)(base + d0 * 128 + (((k0 >> 3) ^ (d0 & 7)) * 16) + hb) =
          make_uint2(lo01, lo23);
      *(uint2*)(base + (d0 + 1) * 128 + (((k0 >> 3) ^ ((d0 + 1) & 7)) * 16) + hb) =
          make_uint2(hi01, hi23);
    }
  };

  float mrun = -3.0e38f, lrun = 0.0f;
  f32x4 o[4] = {};
  char* Pw = (char*)Pl[wv];

  issueK(0, kt0);
  issueV(kt0);
  writeV(0);
  __syncthreads();

  const int NT = SEQ / NSPLIT / 64;
  for (int tt = 0; tt < NT; ++tt) {
    const int cur = tt & 1;
    const bool pf = (tt + 1 < NT);
    if (pf) { issueK(cur ^ 1, kt0 + (tt + 1) * 64); issueV(kt0 + (tt + 1) * 64); }

    // S^T = K . Q^T
    f32x4 sT[4] = {};
    __builtin_amdgcn_s_setprio(1);
    #pragma unroll
    for (int ds = 0; ds < 2; ++ds)
      #pragma unroll
      for (int mf = 0; mf < 4; ++mf) {
        int r = mf * 16 + l15;
        int cb = ds * 4 + l4;
        half8 kf = *(const half8*)(&Kl[cur][r * 64 + ((cb ^ (r & 7)) * 8)]);
        sT[mf] = __builtin_amdgcn_mfma_f32_16x16x32_f16(kf, qf[ds], sT[mf], 0, 0, 0);
      }
    __builtin_amdgcn_s_setprio(0);

    // online softmax over k for q = l15, defer-max THR=8
    float mloc = sT[0][0];
    #pragma unroll
    for (int mf = 0; mf < 4; ++mf)
      #pragma unroll
      for (int r = 0; r < 4; ++r) mloc = fmaxf(mloc, sT[mf][r]);
    mloc = fmaxf(mloc, __shfl_xor(mloc, 16));
    mloc = fmaxf(mloc, __shfl_xor(mloc, 32));
    float corr = 1.0f;
    if (!__all(mloc - mrun <= 8.0f)) {
      float mn = fmaxf(mrun, mloc);
      corr = __expf(mrun - mn);   // first tile: exp(-huge) = 0
      mrun = mn;
      float cr[4];
      #pragma unroll
      for (int r = 0; r < 4; ++r) cr[r] = __shfl(corr, l4 * 4 + r);
      #pragma unroll
      for (int nf = 0; nf < 4; ++nf)
        #pragma unroll
        for (int r = 0; r < 4; ++r) o[nf][r] *= cr[r];
    }
    float ls = 0.f;
    #pragma unroll
    for (int mf = 0; mf < 4; ++mf)
      #pragma unroll
      for (int r = 0; r < 4; ++r) {
        float p = __expf(sT[mf][r] - mrun);
        sT[mf][r] = p;
        ls += p;
      }
    ls += __shfl_xor(ls, 16);
    ls += __shfl_xor(ls, 32);
    lrun = lrun * corr + ls;

    // P -> per-wave LDS, 16B-chunk XOR swizzle (write 8B x4, conflict-free)
    #pragma unroll
    for (int mf = 0; mf < 4; ++mf) {
      union { _Float16 hh[4]; uint2 u; } pk;
      #pragma unroll
      for (int r = 0; r < 4; ++r) pk.hh[r] = (_Float16)sT[mf][r];
      int c = (mf * 2 + (l4 >> 1)) ^ (l15 & 7);
      *(uint2*)(Pw + l15 * 128 + c * 16 + (l4 & 1) * 8) = pk.u;
    }

    if (pf) writeV(cur ^ 1);  // write-late: vreg latency hidden under QK+softmax

    // PV: o[nf] += P[16q x 32k] . V[32k x 16d]
    __builtin_amdgcn_s_setprio(1);
    #pragma unroll
    for (int ks = 0; ks < 2; ++ks) {
      half8 pa = *(const half8*)(Pw + l15 * 128 + (((ks * 4 + l4) ^ (l15 & 7)) * 16));
      #pragma unroll
      for (int nf = 0; nf < 4; ++nf) {
        int d = nf * 16 + l15;
        half8 vb = *(const half8*)((char*)Vt[cur] + d * 128 +
                                   (((ks * 4 + l4) ^ (d & 7)) * 16));
        o[nf] = __builtin_amdgcn_mfma_f32_16x16x32_f16(pa, vb, o[nf], 0, 0, 0);
      }
    }
    __builtin_amdgcn_s_setprio(0);
    __syncthreads();
  }

  // epilogue: normalized partial O + (m,l)
  float lr[4];
  #pragma unroll
  for (int r = 0; r < 4; ++r) lr[r] = 1.0f / __shfl(lrun, l4 * 4 + r);
  _Float16* pz = po + (size_t)z * SEQ * DM;
  #pragma unroll
  for (int nf = 0; nf < 4; ++nf)
    #pragma unroll
    for (int r = 0; r < 4; ++r) {
      int row = q0 + wv * 16 + l4 * 4 + r;
      int col = h * HD + nf * 16 + l15;
      pz[(size_t)row * DM + col] = (_Float16)(o[nf][r] * lr[r]);
    }
  if (l4 == 0) {
    int q = q0 + wv * 16 + l15;
    pm[(z * NH + h) * SEQ + q] = mrun;
    pl[(z * NH + h) * SEQ + q] = lrun;
  }
}

// ---------------------------------------------------------------------------
// Flash-combine the NSPLIT partials into ctx.
// ---------------------------------------------------------------------------
__global__ __launch_bounds__(256)
void merge2(const _Float16* __restrict__ po, const float* __restrict__ pm,
            const float* __restrict__ pl, _Float16* __restrict__ ctx) {
  int e = (blockIdx.x * 256 + threadIdx.x) * 8;   // over SEQ*DM
  int s = e >> 10, h = (e & 1023) >> 6;
  int idx = h * SEQ + s;
  float m1 = pm[idx], m2 = pm[NH * SEQ + idx];
  float l1 = pl[idx], l2 = pl[NH * SEQ + idx];
  float M = fmaxf(m1, m2);
  float w1 = __expf(m1 - M) * l1, w2 = __expf(m2 - M) * l2;
  float inv = 1.0f / (w1 + w2);
  w1 *= inv; w2 *= inv;
  half8 a = *(const half8*)(po + e);
  half8 b = *(const half8*)(po + (size_t)SEQ * DM + e);
  half8 o;
  #pragma unroll
  for (int j = 0; j < 8; ++j)
    o[j] = (_Float16)(w1 * (float)a[j] + w2 * (float)b[j]);
  *(half8*)(ctx + e) = o;
}

// ---------------------------------------------------------------------------
extern "C" void kernel_launch(void* const* d_in, const int* in_sizes, int n_in,
                              void* d_out, int out_size, void* d_ws, size_t ws_size,
                              hipStream_t stream) {
  const float* query = (const float*)d_in[0];
  const float* qkv_w = (const float*)d_in[3];
  const float* qkv_b = (const float*)d_in[4];
  const float* out_w = (const float*)d_in[5];
  const float* out_b = (const float*)d_in[6];
  float* out = (float*)d_out;

  _Float16* Aq   = (_Float16*)d_ws;                 // [0, 4 MiB)
  _Float16* Wqkv = Aq + (size_t)SEQ * DM;           // [4, 10 MiB)
  _Float16* Wout = Wqkv + (size_t)TRI * DM;         // [10, 12 MiB)
  _Float16* qkv  = Wout + (size_t)DM * DM;          // [12, 24 MiB)
  _Float16* ctx  = qkv + (size_t)SEQ * TRI;         // [24, 28 MiB)
  float2*   tab  = (float2*)(ctx + (size_t)SEQ * DM); // [28, 28.5 MiB)
  // partials alias the dead Aq/Wqkv region after the QKV GEMM:
  _Float16* po = (_Float16*)d_ws;                   // [0, 8 MiB)
  float*    pm = (float*)((char*)d_ws + (8u << 20)); // [8, 8.25 MiB)
  float*    pl = pm + NSPLIT * NH * SEQ;             // [8.25, 8.5 MiB)

  cvt3<<<6400, 256, 0, stream>>>(query, qkv_w, out_w, Aq, Wqkv, Wout, tab,
                                 SEQ * DM, TRI * DM);

  gemm_dbuf<1, _Float16><<<dim3(TRI / 128, SEQ / 64), 256, 0, stream>>>(
      Aq, Wqkv, qkv_b, tab, qkv, SEQ, TRI, DM);

  attn_f16<<<dim3(SEQ / 64, NH, NSPLIT), 256, 0, stream>>>(qkv, po, pm, pl);

  merge2<<<SEQ * DM / 8 / 256, 256, 0, stream>>>(po, pm, pl, ctx);

  gemm_dbuf<0, float><<<dim3(DM / 128, SEQ / 64), 256, 0, stream>>>(
      ctx, Wout, out_b, nullptr, out, SEQ, DM, DM);
}